// Round 7
// baseline (795.395 us; speedup 1.0000x reference)
//
#include <hip/hip_runtime.h>

#define Bq 16
#define Nq 2048
#define Sq 4096
#define Dq 128
#define NNZq 1048576
#define ROWS (Bq * Nq)   // 32768
#define NBIN 512         // coarse bins, 64 consecutive rows each
#define RPB 64           // rows per bin
#define BCAP 2560        // bin capacity (mean fill 2048, +11 sigma)
#define OVF_MAX 65536
#define EPT 16           // entries per thread in bin pass
#define TPB 256

typedef unsigned long long u64;
typedef float vfloat4 __attribute__((ext_vector_type(4)));

// ---------- Pass A: coarse-bin radix scatter (block-aggregated, dense writes) ----------
// Each block: 4096 contiguous nz -> LDS histogram over 512 bins -> one global
// atomic per nonempty bin -> packed 8B entries written in per-bin contiguous runs
// (avg 8 entries = full cacheline, same XCD -> L2 merges -> ~1x write amp).
__global__ __launch_bounds__(TPB) void bin_kernel(
    const int* __restrict__ subnode_ids,   // [B,S]
    const int* __restrict__ mb,            // [NNZ]
    const int* __restrict__ mn,            // [NNZ]
    const int* __restrict__ ms,            // [NNZ]
    const float* __restrict__ mv,          // [NNZ]
    int* __restrict__ binCnt,              // [NBIN] (zeroed)
    u64* __restrict__ binMem,              // [NBIN*BCAP] packed entries
    int* __restrict__ ovfn,                // overflow counter (zeroed)
    int* __restrict__ ovf)                 // overflow nz list
{
    __shared__ int hist[NBIN];
    __shared__ int base[NBIN];
    int t = threadIdx.x;
    for (int g = t; g < NBIN; g += TPB) hist[g] = 0;
    __syncthreads();

    int blockBase = blockIdx.x * (TPB * EPT);
    int g[EPT], rank[EPT];
    u64 pk[EPT];
    #pragma unroll
    for (int k = 0; k < EPT; k++) {        // coalesced index loads + L2 token gather
        int i   = blockBase + k * TPB + t;
        int b   = mb[i];
        int row = b * Nq + mn[i];
        int tok = subnode_ids[b * Sq + ms[i]];
        float v = mv[i];
        g[k]  = row >> 6;                  // coarse bin
        pk[k] = ((u64)(unsigned)__float_as_int(v) << 32)
              | ((u64)(row & 63) << 16)
              | (unsigned)tok;             // tok < 65536 fits 16 bits
        rank[k] = atomicAdd(&hist[g[k]], 1);   // LDS atomic: within-block rank
    }
    __syncthreads();
    for (int gg = t; gg < NBIN; gg += TPB) {   // one global atomic per nonempty bin
        int h = hist[gg];
        base[gg] = h ? atomicAdd(&binCnt[gg], h) : 0;
    }
    __syncthreads();
    #pragma unroll
    for (int k = 0; k < EPT; k++) {
        int p = base[g[k]] + rank[k];
        if (p < BCAP) {
            binMem[(size_t)g[k] * BCAP + p] = pk[k];
        } else {
            int o = atomicAdd(ovfn, 1);
            if (o < OVF_MAX) ovf[o] = blockBase + k * TPB + t;
        }
    }
}

// ---------- Pass B: per-bin pool with LDS accumulators ----------
// One block per bin (64 rows x 128 dims = 32 KB LDS). Lane t owns dims
// {t, t+32, t+64, t+96} -> stride-1 LDS banks (2-way alias across the two
// 32-groups of a wave = free). Final store: 32 KB fully-coalesced stream.
__global__ __launch_bounds__(TPB) void pool_kernel(
    const float* __restrict__ emb,       // [VOCAB,D]
    const int* __restrict__ binCnt,      // [NBIN]
    const u64* __restrict__ binMem,      // [NBIN*BCAP]
    float* __restrict__ out)             // [ROWS,D]
{
    __shared__ float acc[RPB * Dq];      // 32 KB
    int t = threadIdx.x;
    for (int i = t; i < RPB * Dq; i += TPB) acc[i] = 0.f;
    __syncthreads();

    int bin  = blockIdx.x;
    int n    = min(binCnt[bin], BCAP);
    const u64* bm = binMem + (size_t)bin * BCAP;
    int gi   = t >> 5;       // 8 groups of 32 lanes
    int lane = t & 31;

    for (int e = gi; e < n; e += 8) {
        u64 pk  = bm[e];                             // broadcast load within group
        int tok = (int)(pk & 0xFFFF);
        int rl  = (int)((pk >> 16) & 63);
        float v = __int_as_float((int)(pk >> 32));
        const float* er = emb + (size_t)tok * Dq;
        float e0 = er[lane];                         // 4 coalesced 128B group-loads
        float e1 = er[lane + 32];
        float e2 = er[lane + 64];
        float e3 = er[lane + 96];
        float* ar = acc + rl * Dq;
        atomicAdd(ar + lane,      e0 * v);           // ds_add_f32, conflict-free banks
        atomicAdd(ar + lane + 32, e1 * v);
        atomicAdd(ar + lane + 64, e2 * v);
        atomicAdd(ar + lane + 96, e3 * v);
    }
    __syncthreads();

    // Bin's 64 output rows are contiguous: out + bin*32KB, streaming store.
    vfloat4* o = reinterpret_cast<vfloat4*>(out + (size_t)bin * RPB * Dq);
    const vfloat4* a = reinterpret_cast<const vfloat4*>(acc);
    for (int i = t; i < (RPB * Dq) / 4; i += TPB)
        __builtin_nontemporal_store(a[i], o + i);
}

// ---------- Pass C: rare-overflow fallback (usually 0 entries) ----------
__global__ __launch_bounds__(TPB) void overflow_kernel(
    const int* __restrict__ subnode_ids,
    const int* __restrict__ mb, const int* __restrict__ mn,
    const int* __restrict__ ms, const float* __restrict__ mv,
    const float* __restrict__ emb,
    const int* __restrict__ ovfn, const int* __restrict__ ovf,
    float* __restrict__ out)
{
    int nov = min(*ovfn, OVF_MAX);
    for (int e = blockIdx.x * TPB + threadIdx.x; e < nov; e += gridDim.x * TPB) {
        int i = ovf[e];
        int b = mb[i];
        int row = b * Nq + mn[i];
        int tok = subnode_ids[b * Sq + ms[i]];
        float v = mv[i];
        const float* src = emb + (size_t)tok * Dq;
        float* dst = out + (size_t)row * Dq;
        for (int d = 0; d < Dq; d++) unsafeAtomicAdd(dst + d, src[d] * v);
    }
}

extern "C" void kernel_launch(void* const* d_in, const int* in_sizes, int n_in,
                              void* d_out, int out_size, void* d_ws, size_t ws_size,
                              hipStream_t stream) {
    const int*   subnode_ids  = (const int*)d_in[0];
    const int*   mask_batch   = (const int*)d_in[1];
    const int*   mask_node    = (const int*)d_in[2];
    const int*   mask_subnode = (const int*)d_in[3];
    const float* mask_values  = (const float*)d_in[4];
    const float* emb_table    = (const float*)d_in[5];
    float*       out          = (float*)d_out;

    // ws layout: binMem[NBIN*BCAP] (u64, 10.5 MB) | binCnt[NBIN] | ovfn[1] pad[63] | ovf[OVF_MAX]
    u64* binMem = (u64*)d_ws;
    int* binCnt = (int*)(binMem + (size_t)NBIN * BCAP);
    int* ovfn   = binCnt + NBIN;
    int* ovf    = ovfn + 64;

    // Zero bin counters + overflow counter only.
    (void)hipMemsetAsync(binCnt, 0, (NBIN + 64) * sizeof(int), stream);

    bin_kernel<<<NNZq / (TPB * EPT), TPB, 0, stream>>>(
        subnode_ids, mask_batch, mask_node, mask_subnode, mask_values,
        binCnt, binMem, ovfn, ovf);
    pool_kernel<<<NBIN, TPB, 0, stream>>>(
        emb_table, binCnt, binMem, out);
    overflow_kernel<<<32, TPB, 0, stream>>>(
        subnode_ids, mask_batch, mask_node, mask_subnode, mask_values,
        emb_table, ovfn, ovf, out);
}

// Round 8
// 171.025 us; speedup vs baseline: 4.6508x; 4.6508x over previous
//
#include <hip/hip_runtime.h>

#define Bq 16
#define Nq 2048
#define Sq 4096
#define Dq 128
#define NNZq 1048576
#define ROWS (Bq * Nq)   // 32768
#define NBIN 1024        // coarse bins
#define RPB 32           // rows per bin
#define BCAP 1280        // bin capacity (mean 1024, +8 sigma)
#define OVF_MAX 65536
#define BTPB 1024        // bin kernel threads (16 waves -> latency hiding)
#define BEPT 4           // bin kernel entries/thread (4096 per block)

typedef unsigned long long u64;
typedef float vfloat4 __attribute__((ext_vector_type(4)));

// ---------- Pass A: coarse-bin radix scatter (block-aggregated writes) ----------
// 256 blocks x 1024 threads; each block bins 4096 contiguous nz via LDS
// histogram, reserves space with one global atomic per bin, writes packed
// 8B entries in per-bin runs of ~4 (32B) -> L2-merged, ~1.5-2x write amp.
__global__ __launch_bounds__(BTPB) void bin_kernel(
    const int* __restrict__ subnode_ids,   // [B,S]
    const int* __restrict__ mb,            // [NNZ]
    const int* __restrict__ mn,            // [NNZ]
    const int* __restrict__ ms,            // [NNZ]
    const float* __restrict__ mv,          // [NNZ]
    int* __restrict__ binCnt,              // [NBIN] (zeroed)
    u64* __restrict__ binMem,              // [NBIN*BCAP] packed entries
    int* __restrict__ ovfn,                // overflow counter (zeroed)
    int* __restrict__ ovf)                 // overflow nz list
{
    __shared__ int hist[NBIN];
    __shared__ int base[NBIN];
    int t = threadIdx.x;
    for (int g = t; g < NBIN; g += BTPB) hist[g] = 0;
    __syncthreads();

    int blockBase = blockIdx.x * (BTPB * BEPT);
    int g[BEPT], rank[BEPT];
    u64 pk[BEPT];
    #pragma unroll
    for (int k = 0; k < BEPT; k++) {       // coalesced index loads + L2 token gather
        int i   = blockBase + k * BTPB + t;
        int b   = mb[i];
        int row = b * Nq + mn[i];
        int tok = subnode_ids[b * Sq + ms[i]];
        float v = mv[i];
        g[k]  = row >> 5;                  // coarse bin (32 rows)
        pk[k] = ((u64)(unsigned)__float_as_int(v) << 32)
              | ((u64)(row & 31) << 16)
              | (unsigned)tok;             // tok < 65536 fits 16 bits
        rank[k] = atomicAdd(&hist[g[k]], 1);
    }
    __syncthreads();
    for (int gg = t; gg < NBIN; gg += BTPB) {
        int h = hist[gg];
        base[gg] = h ? atomicAdd(&binCnt[gg], h) : 0;
    }
    __syncthreads();
    #pragma unroll
    for (int k = 0; k < BEPT; k++) {
        int p = base[g[k]] + rank[k];
        if (p < BCAP) {
            binMem[(size_t)g[k] * BCAP + p] = pk[k];
        } else {
            int o = atomicAdd(ovfn, 1);
            if (o < OVF_MAX) ovf[o] = blockBase + k * BTPB + t;
        }
    }
}

// ---------- Pass B: fused in-LDS counting sort + register-acc pool ----------
// One 256-thread block per bin (block owns its 32 output rows exclusively).
// Sort ~1024 entries by local row into LDS, then 8 groups of 32 lanes do
// register accumulation with 8 gathers in flight (R5-pool structure), one
// NT 512B store per row. 1024 blocks x 8 groups x MLP8 = 64K outstanding.
__global__ __launch_bounds__(256) void pool_kernel(
    const float* __restrict__ emb,       // [VOCAB,D]
    const int* __restrict__ binCnt,      // [NBIN]
    const u64* __restrict__ binMem,      // [NBIN*BCAP]
    float* __restrict__ out)             // [ROWS,D]
{
    __shared__ u64 ebuf[BCAP];           // 10 KB sorted entries
    __shared__ int hist[RPB];
    __shared__ int start[RPB + 1];
    __shared__ int cursor[RPB];

    int t   = threadIdx.x;
    int bin = blockIdx.x;
    if (t < RPB) hist[t] = 0;
    __syncthreads();

    int n = min(binCnt[bin], BCAP);
    const u64* bm = binMem + (size_t)bin * BCAP;

    // count per local row
    for (int e = t; e < n; e += 256) {
        int rl = (int)((bm[e] >> 16) & 31);
        atomicAdd(&hist[rl], 1);
    }
    __syncthreads();
    // exclusive prefix over 32 counters (single 32-lane scan)
    if (t < 32) {
        int v = hist[t];
        #pragma unroll
        for (int d = 1; d < 32; d <<= 1) {
            int w = __shfl_up(v, d, 32);
            if (t >= d) v += w;
        }
        start[t + 1] = v;
        if (t == 0) start[0] = 0;
    }
    __syncthreads();
    if (t < RPB) cursor[t] = start[t];
    __syncthreads();
    // place entries compactly by row
    for (int e = t; e < n; e += 256) {
        u64 pk = bm[e];
        int rl = (int)((pk >> 16) & 31);
        int p  = atomicAdd(&cursor[rl], 1);
        ebuf[p] = pk;
    }
    __syncthreads();

    // pool: 8 groups of 32 lanes, 4 rows per group, entries from LDS broadcast
    int gi   = t >> 5;
    int lane = t & 31;
    for (int rr = 0; rr < 4; rr++) {
        int r  = gi * 4 + rr;
        int s0 = start[r], s1 = start[r + 1];
        vfloat4 acc = {0.f, 0.f, 0.f, 0.f};
        int k = s0;
        for (; k + 8 <= s1; k += 8) {      // 8 independent 512B row-gathers in flight
            int   tk[8];
            float vv[8];
            #pragma unroll
            for (int u = 0; u < 8; u++) {
                u64 pk = ebuf[k + u];      // same addr for all 32 lanes -> broadcast
                tk[u] = (int)(pk & 0xFFFF);
                vv[u] = __int_as_float((int)(pk >> 32));
            }
            vfloat4 e[8];
            #pragma unroll
            for (int u = 0; u < 8; u++)
                e[u] = reinterpret_cast<const vfloat4*>(emb + (size_t)tk[u] * Dq)[lane];
            #pragma unroll
            for (int u = 0; u < 8; u++)
                acc += e[u] * vv[u];
        }
        for (; k < s1; k++) {
            u64 pk = ebuf[k];
            int   tok = (int)(pk & 0xFFFF);
            float v   = __int_as_float((int)(pk >> 32));
            acc += reinterpret_cast<const vfloat4*>(emb + (size_t)tok * Dq)[lane] * v;
        }
        __builtin_nontemporal_store(
            acc, reinterpret_cast<vfloat4*>(out + ((size_t)bin * RPB + r) * Dq) + lane);
    }
}

// ---------- Pass C: rare-overflow fallback (usually 0 entries) ----------
__global__ __launch_bounds__(256) void overflow_kernel(
    const int* __restrict__ subnode_ids,
    const int* __restrict__ mb, const int* __restrict__ mn,
    const int* __restrict__ ms, const float* __restrict__ mv,
    const float* __restrict__ emb,
    const int* __restrict__ ovfn, const int* __restrict__ ovf,
    float* __restrict__ out)
{
    int nov = min(*ovfn, OVF_MAX);
    for (int e = blockIdx.x * 256 + threadIdx.x; e < nov; e += gridDim.x * 256) {
        int i = ovf[e];
        int b = mb[i];
        int row = b * Nq + mn[i];
        int tok = subnode_ids[b * Sq + ms[i]];
        float v = mv[i];
        const float* src = emb + (size_t)tok * Dq;
        float* dst = out + (size_t)row * Dq;
        for (int d = 0; d < Dq; d++) unsafeAtomicAdd(dst + d, src[d] * v);
    }
}

extern "C" void kernel_launch(void* const* d_in, const int* in_sizes, int n_in,
                              void* d_out, int out_size, void* d_ws, size_t ws_size,
                              hipStream_t stream) {
    const int*   subnode_ids  = (const int*)d_in[0];
    const int*   mask_batch   = (const int*)d_in[1];
    const int*   mask_node    = (const int*)d_in[2];
    const int*   mask_subnode = (const int*)d_in[3];
    const float* mask_values  = (const float*)d_in[4];
    const float* emb_table    = (const float*)d_in[5];
    float*       out          = (float*)d_out;

    // ws layout: binMem[NBIN*BCAP] (u64, 10.5 MB) | binCnt[NBIN] | ovfn[1] pad[63] | ovf[OVF_MAX]
    u64* binMem = (u64*)d_ws;
    int* binCnt = (int*)(binMem + (size_t)NBIN * BCAP);
    int* ovfn   = binCnt + NBIN;
    int* ovf    = ovfn + 64;

    (void)hipMemsetAsync(binCnt, 0, (NBIN + 64) * sizeof(int), stream);

    bin_kernel<<<NNZq / (BTPB * BEPT), BTPB, 0, stream>>>(
        subnode_ids, mask_batch, mask_node, mask_subnode, mask_values,
        binCnt, binMem, ovfn, ovf);
    pool_kernel<<<NBIN, 256, 0, stream>>>(
        emb_table, binCnt, binMem, out);
    overflow_kernel<<<32, 256, 0, stream>>>(
        subnode_ids, mask_batch, mask_node, mask_subnode, mask_values,
        emb_table, ovfn, ovf, out);
}

// Round 9
// 143.207 us; speedup vs baseline: 5.5542x; 1.1942x over previous
//
#include <hip/hip_runtime.h>
#include <hip/hip_fp16.h>

#define Bq 16
#define Nq 2048
#define Sq 4096
#define Dq 128
#define VOCABq 50257
#define NNZq 1048576
#define ROWS (Bq * Nq)   // 32768
#define NBIN 1024        // coarse bins
#define RPB 32           // rows per bin
#define BCAP 1280        // bin capacity (mean 1024, +8 sigma)
#define OVF_MAX 65536
#define BTPB 1024        // bin kernel threads
#define BEPT 4           // bin kernel entries/thread

typedef unsigned long long u64;
typedef float vfloat4 __attribute__((ext_vector_type(4)));
typedef unsigned short vushort4 __attribute__((ext_vector_type(4)));

// ---------- Pass 0: cast emb table fp32 -> fp16 (rows 512B -> 256B) ----------
__global__ __launch_bounds__(256) void cast_kernel(
    const float* __restrict__ emb, unsigned short* __restrict__ emb16)
{
    const int NQUAD = (VOCABq * Dq) / 4;  // 1,608,224
    int i = blockIdx.x * 256 + threadIdx.x;
    if (i >= NQUAD) return;
    vfloat4 f = reinterpret_cast<const vfloat4*>(emb)[i];
    vushort4 h;
    h.x = __half_as_ushort(__float2half_rn(f.x));
    h.y = __half_as_ushort(__float2half_rn(f.y));
    h.z = __half_as_ushort(__float2half_rn(f.z));
    h.w = __half_as_ushort(__float2half_rn(f.w));
    __builtin_nontemporal_store(h, reinterpret_cast<vushort4*>(emb16) + i);
}

// ---------- Pass A: coarse-bin radix scatter (block-aggregated writes) ----------
__global__ __launch_bounds__(BTPB) void bin_kernel(
    const int* __restrict__ subnode_ids,   // [B,S]
    const int* __restrict__ mb,            // [NNZ]
    const int* __restrict__ mn,            // [NNZ]
    const int* __restrict__ ms,            // [NNZ]
    const float* __restrict__ mv,          // [NNZ]
    int* __restrict__ binCnt,              // [NBIN] (zeroed)
    u64* __restrict__ binMem,              // [NBIN*BCAP] packed entries
    int* __restrict__ ovfn,                // overflow counter (zeroed)
    int* __restrict__ ovf)                 // overflow nz list
{
    __shared__ int hist[NBIN];
    __shared__ int base[NBIN];
    int t = threadIdx.x;
    for (int g = t; g < NBIN; g += BTPB) hist[g] = 0;
    __syncthreads();

    int blockBase = blockIdx.x * (BTPB * BEPT);
    int g[BEPT], rank[BEPT];
    u64 pk[BEPT];
    #pragma unroll
    for (int k = 0; k < BEPT; k++) {       // coalesced index loads + L2 token gather
        int i   = blockBase + k * BTPB + t;
        int b   = mb[i];
        int row = b * Nq + mn[i];
        int tok = subnode_ids[b * Sq + ms[i]];
        float v = mv[i];
        g[k]  = row >> 5;                  // coarse bin (32 rows)
        pk[k] = ((u64)(unsigned)__float_as_int(v) << 32)
              | ((u64)(row & 31) << 16)
              | (unsigned)tok;             // tok < 65536 fits 16 bits
        rank[k] = atomicAdd(&hist[g[k]], 1);
    }
    __syncthreads();
    for (int gg = t; gg < NBIN; gg += BTPB) {
        int h = hist[gg];
        base[gg] = h ? atomicAdd(&binCnt[gg], h) : 0;
    }
    __syncthreads();
    #pragma unroll
    for (int k = 0; k < BEPT; k++) {
        int p = base[g[k]] + rank[k];
        if (p < BCAP) {
            binMem[(size_t)g[k] * BCAP + p] = pk[k];
        } else {
            int o = atomicAdd(ovfn, 1);
            if (o < OVF_MAX) ovf[o] = blockBase + k * BTPB + t;
        }
    }
}

// ---------- Pass B: fused in-LDS counting sort + register-acc pool (fp16 gather) ----------
// One 256-thread block per bin. Sort entries by local row into LDS, then 8
// groups of 32 lanes accumulate 4 rows each: lane t owns dims 4t..4t+3, one
// 8B fp16 load per entry (256B/row per group), fp32 accumulate, NT store.
__global__ __launch_bounds__(256) void pool_kernel(
    const unsigned short* __restrict__ emb16,  // [VOCAB,D] fp16
    const int* __restrict__ binCnt,            // [NBIN]
    const u64* __restrict__ binMem,            // [NBIN*BCAP]
    float* __restrict__ out)                   // [ROWS,D]
{
    __shared__ u64 ebuf[BCAP];           // 10 KB sorted entries
    __shared__ int hist[RPB];
    __shared__ int start[RPB + 1];
    __shared__ int cursor[RPB];

    int t   = threadIdx.x;
    int bin = blockIdx.x;
    if (t < RPB) hist[t] = 0;
    __syncthreads();

    int n = min(binCnt[bin], BCAP);
    const u64* bm = binMem + (size_t)bin * BCAP;

    for (int e = t; e < n; e += 256) {
        int rl = (int)((bm[e] >> 16) & 31);
        atomicAdd(&hist[rl], 1);
    }
    __syncthreads();
    if (t < 32) {
        int v = hist[t];
        #pragma unroll
        for (int d = 1; d < 32; d <<= 1) {
            int w = __shfl_up(v, d, 32);
            if (t >= d) v += w;
        }
        start[t + 1] = v;
        if (t == 0) start[0] = 0;
    }
    __syncthreads();
    if (t < RPB) cursor[t] = start[t];
    __syncthreads();
    for (int e = t; e < n; e += 256) {
        u64 pk = bm[e];
        int rl = (int)((pk >> 16) & 31);
        int p  = atomicAdd(&cursor[rl], 1);
        ebuf[p] = pk;
    }
    __syncthreads();

    int gi   = t >> 5;
    int lane = t & 31;
    for (int rr = 0; rr < 4; rr++) {
        int r  = gi * 4 + rr;
        int s0 = start[r], s1 = start[r + 1];
        vfloat4 acc = {0.f, 0.f, 0.f, 0.f};
        int k = s0;
        for (; k + 8 <= s1; k += 8) {      // 8 independent 256B row-gathers in flight
            int   tk[8];
            float vv[8];
            #pragma unroll
            for (int u = 0; u < 8; u++) {
                u64 pk = ebuf[k + u];      // same addr for all 32 lanes -> broadcast
                tk[u] = (int)(pk & 0xFFFF);
                vv[u] = __int_as_float((int)(pk >> 32));
            }
            vushort4 e[8];
            #pragma unroll
            for (int u = 0; u < 8; u++)
                e[u] = reinterpret_cast<const vushort4*>(emb16 + (size_t)tk[u] * Dq)[lane];
            #pragma unroll
            for (int u = 0; u < 8; u++) {
                acc.x += __half2float(__ushort_as_half(e[u].x)) * vv[u];
                acc.y += __half2float(__ushort_as_half(e[u].y)) * vv[u];
                acc.z += __half2float(__ushort_as_half(e[u].z)) * vv[u];
                acc.w += __half2float(__ushort_as_half(e[u].w)) * vv[u];
            }
        }
        for (; k < s1; k++) {
            u64 pk = ebuf[k];
            int   tok = (int)(pk & 0xFFFF);
            float v   = __int_as_float((int)(pk >> 32));
            vushort4 e = reinterpret_cast<const vushort4*>(emb16 + (size_t)tok * Dq)[lane];
            acc.x += __half2float(__ushort_as_half(e.x)) * v;
            acc.y += __half2float(__ushort_as_half(e.y)) * v;
            acc.z += __half2float(__ushort_as_half(e.z)) * v;
            acc.w += __half2float(__ushort_as_half(e.w)) * v;
        }
        __builtin_nontemporal_store(
            acc, reinterpret_cast<vfloat4*>(out + ((size_t)bin * RPB + r) * Dq) + lane);
    }
}

// ---------- Pass C: rare-overflow fallback (usually 0 entries, fp32 emb) ----------
__global__ __launch_bounds__(256) void overflow_kernel(
    const int* __restrict__ subnode_ids,
    const int* __restrict__ mb, const int* __restrict__ mn,
    const int* __restrict__ ms, const float* __restrict__ mv,
    const float* __restrict__ emb,
    const int* __restrict__ ovfn, const int* __restrict__ ovf,
    float* __restrict__ out)
{
    int nov = min(*ovfn, OVF_MAX);
    for (int e = blockIdx.x * 256 + threadIdx.x; e < nov; e += gridDim.x * 256) {
        int i = ovf[e];
        int b = mb[i];
        int row = b * Nq + mn[i];
        int tok = subnode_ids[b * Sq + ms[i]];
        float v = mv[i];
        const float* src = emb + (size_t)tok * Dq;
        float* dst = out + (size_t)row * Dq;
        for (int d = 0; d < Dq; d++) unsafeAtomicAdd(dst + d, src[d] * v);
    }
}

extern "C" void kernel_launch(void* const* d_in, const int* in_sizes, int n_in,
                              void* d_out, int out_size, void* d_ws, size_t ws_size,
                              hipStream_t stream) {
    const int*   subnode_ids  = (const int*)d_in[0];
    const int*   mask_batch   = (const int*)d_in[1];
    const int*   mask_node    = (const int*)d_in[2];
    const int*   mask_subnode = (const int*)d_in[3];
    const float* mask_values  = (const float*)d_in[4];
    const float* emb_table    = (const float*)d_in[5];
    float*       out          = (float*)d_out;

    // ws layout: emb16[VOCAB*D halves, 12.86 MB] | binMem[NBIN*BCAP u64, 10.49 MB]
    //          | binCnt[NBIN] | ovfn[1] pad[63] | ovf[OVF_MAX]   (~23.6 MB total)
    unsigned short* emb16 = (unsigned short*)d_ws;
    u64* binMem = (u64*)(emb16 + (size_t)VOCABq * Dq + 64 /*align pad*/);
    int* binCnt = (int*)(binMem + (size_t)NBIN * BCAP);
    int* ovfn   = binCnt + NBIN;
    int* ovf    = ovfn + 64;

    (void)hipMemsetAsync(binCnt, 0, (NBIN + 64) * sizeof(int), stream);

    const int NQUAD = (VOCABq * Dq) / 4;
    cast_kernel<<<(NQUAD + 255) / 256, 256, 0, stream>>>(emb_table, emb16);
    bin_kernel<<<NNZq / (BTPB * BEPT), BTPB, 0, stream>>>(
        subnode_ids, mask_batch, mask_node, mask_subnode, mask_values,
        binCnt, binMem, ovfn, ovf);
    pool_kernel<<<NBIN, 256, 0, stream>>>(emb16, binCnt, binMem, out);
    overflow_kernel<<<32, 256, 0, stream>>>(
        subnode_ids, mask_batch, mask_node, mask_subnode, mask_values,
        emb_table, ovfn, ovf, out);
}

// Round 10
// 137.671 us; speedup vs baseline: 5.7775x; 1.0402x over previous
//
#include <hip/hip_runtime.h>
#include <hip/hip_fp16.h>

#define Bq 16
#define Nq 2048
#define Sq 4096
#define Dq 128
#define VOCABq 50257
#define NNZq 1048576
#define ROWS (Bq * Nq)   // 32768
#define NBIN 2048        // coarse bins
#define RPB 16           // rows per bin
#define BCAP 768         // bin capacity (mean 512, +11 sigma)
#define OVF_MAX 65536
#define BTPB 1024        // bin kernel threads
#define BEPT 4           // bin kernel entries/thread

typedef unsigned long long u64;
typedef float vfloat4 __attribute__((ext_vector_type(4)));
typedef unsigned short vushort4 __attribute__((ext_vector_type(4)));
typedef unsigned short vushort8 __attribute__((ext_vector_type(8)));

// ---------- Pass 0: cast emb table fp32 -> fp16 (rows 512B -> 256B) ----------
__global__ __launch_bounds__(256) void cast_kernel(
    const float* __restrict__ emb, unsigned short* __restrict__ emb16)
{
    const int NQUAD = (VOCABq * Dq) / 4;  // 1,608,224
    int i = blockIdx.x * 256 + threadIdx.x;
    if (i >= NQUAD) return;
    vfloat4 f = reinterpret_cast<const vfloat4*>(emb)[i];
    vushort4 h;
    h.x = __half_as_ushort(__float2half_rn(f.x));
    h.y = __half_as_ushort(__float2half_rn(f.y));
    h.z = __half_as_ushort(__float2half_rn(f.z));
    h.w = __half_as_ushort(__float2half_rn(f.w));
    __builtin_nontemporal_store(h, reinterpret_cast<vushort4*>(emb16) + i);
}

// ---------- Pass A: coarse-bin radix scatter (block-aggregated writes) ----------
__global__ __launch_bounds__(BTPB) void bin_kernel(
    const int* __restrict__ subnode_ids,   // [B,S]
    const int* __restrict__ mb,            // [NNZ]
    const int* __restrict__ mn,            // [NNZ]
    const int* __restrict__ ms,            // [NNZ]
    const float* __restrict__ mv,          // [NNZ]
    int* __restrict__ binCnt,              // [NBIN] (zeroed)
    u64* __restrict__ binMem,              // [NBIN*BCAP] packed entries
    int* __restrict__ ovfn,                // overflow counter (zeroed)
    int* __restrict__ ovf)                 // overflow nz list
{
    __shared__ int hist[NBIN];
    __shared__ int base[NBIN];
    int t = threadIdx.x;
    for (int g = t; g < NBIN; g += BTPB) hist[g] = 0;
    __syncthreads();

    int blockBase = blockIdx.x * (BTPB * BEPT);
    int g[BEPT], rank[BEPT];
    u64 pk[BEPT];
    #pragma unroll
    for (int k = 0; k < BEPT; k++) {       // coalesced index loads + L2 token gather
        int i   = blockBase + k * BTPB + t;
        int b   = mb[i];
        int row = b * Nq + mn[i];
        int tok = subnode_ids[b * Sq + ms[i]];
        float v = mv[i];
        g[k]  = row >> 4;                  // coarse bin (16 rows)
        pk[k] = ((u64)(unsigned)__float_as_int(v) << 32)
              | ((u64)(row & 15) << 16)
              | (unsigned)tok;             // tok < 65536 fits 16 bits
        rank[k] = atomicAdd(&hist[g[k]], 1);
    }
    __syncthreads();
    for (int gg = t; gg < NBIN; gg += BTPB) {
        int h = hist[gg];
        base[gg] = h ? atomicAdd(&binCnt[gg], h) : 0;
    }
    __syncthreads();
    #pragma unroll
    for (int k = 0; k < BEPT; k++) {
        int p = base[g[k]] + rank[k];
        if (p < BCAP) {
            binMem[(size_t)g[k] * BCAP + p] = pk[k];
        } else {
            int o = atomicAdd(ovfn, 1);
            if (o < OVF_MAX) ovf[o] = blockBase + k * BTPB + t;
        }
    }
}

// ---------- Pass B: in-LDS sort by (token-quarter, row) + phased pool ----------
// One 256-thread block per bin (16 rows). Sort key = (tok>>14)<<4 | row_local:
// the block processes entries in 4 token-range phases (~3.2MB table slice,
// L2-resident across co-resident blocks). 16 groups of 16 lanes; group g owns
// row g (lane = 16B ushort8 slice); acc in fp32 regs; one NT 512B store/row.
__global__ __launch_bounds__(256) void pool_kernel(
    const unsigned short* __restrict__ emb16,  // [VOCAB,D] fp16
    const int* __restrict__ binCnt,            // [NBIN]
    const u64* __restrict__ binMem,            // [NBIN*BCAP]
    float* __restrict__ out)                   // [ROWS,D]
{
    __shared__ u64 ebuf[BCAP];           // 6 KB sorted entries
    __shared__ int hist[64];
    __shared__ int start[65];
    __shared__ int cursor[64];

    int t   = threadIdx.x;
    int bin = blockIdx.x;
    if (t < 64) hist[t] = 0;
    __syncthreads();

    int n = min(binCnt[bin], BCAP);
    const u64* bm = binMem + (size_t)bin * BCAP;

    // stage entries (<=3 per thread) + histogram 64 keys
    u64 myPk[3];
    int myKey[3], myCnt = 0;
    for (int e = t; e < n; e += 256) {
        u64 pk  = bm[e];
        int tok = (int)(pk & 0xFFFF);
        int key = ((tok >> 14) << 4) | (int)((pk >> 16) & 15);
        myPk[myCnt] = pk; myKey[myCnt] = key; myCnt++;
        atomicAdd(&hist[key], 1);
    }
    __syncthreads();
    // exclusive prefix over 64 counters: threads 0..63 are wave 0
    if (t < 64) {
        int v = hist[t];
        #pragma unroll
        for (int d = 1; d < 64; d <<= 1) {
            int w = __shfl_up(v, d, 64);
            if (t >= d) v += w;
        }
        start[t + 1] = v;
        if (t == 0) start[0] = 0;
    }
    __syncthreads();
    if (t < 64) cursor[t] = start[t];
    __syncthreads();
    for (int k = 0; k < myCnt; k++) {
        int p = atomicAdd(&cursor[myKey[k]], 1);
        ebuf[p] = myPk[k];
    }
    __syncthreads();

    // pool: group g (16 lanes) owns row g; 4 token-quarter phases
    int g    = t >> 4;
    int lane = t & 15;
    vfloat4 a0 = {0.f, 0.f, 0.f, 0.f};
    vfloat4 a1 = {0.f, 0.f, 0.f, 0.f};
    #pragma unroll
    for (int q = 0; q < 4; q++) {
        int s0 = start[q * 16 + g], s1 = start[q * 16 + g + 1];
        int k = s0;
        for (; k + 8 <= s1; k += 8) {      // 8 independent 256B row-gathers in flight
            int   tk[8];
            float vv[8];
            #pragma unroll
            for (int u = 0; u < 8; u++) {
                u64 pk = ebuf[k + u];      // same addr within group -> broadcast
                tk[u] = (int)(pk & 0xFFFF);
                vv[u] = __int_as_float((int)(pk >> 32));
            }
            vushort8 e[8];
            #pragma unroll
            for (int u = 0; u < 8; u++)
                e[u] = reinterpret_cast<const vushort8*>(emb16 + (size_t)tk[u] * Dq)[lane];
            #pragma unroll
            for (int u = 0; u < 8; u++) {
                a0.x += __half2float(__ushort_as_half(e[u][0])) * vv[u];
                a0.y += __half2float(__ushort_as_half(e[u][1])) * vv[u];
                a0.z += __half2float(__ushort_as_half(e[u][2])) * vv[u];
                a0.w += __half2float(__ushort_as_half(e[u][3])) * vv[u];
                a1.x += __half2float(__ushort_as_half(e[u][4])) * vv[u];
                a1.y += __half2float(__ushort_as_half(e[u][5])) * vv[u];
                a1.z += __half2float(__ushort_as_half(e[u][6])) * vv[u];
                a1.w += __half2float(__ushort_as_half(e[u][7])) * vv[u];
            }
        }
        for (; k < s1; k++) {
            u64 pk = ebuf[k];
            int   tok = (int)(pk & 0xFFFF);
            float v   = __int_as_float((int)(pk >> 32));
            vushort8 e = reinterpret_cast<const vushort8*>(emb16 + (size_t)tok * Dq)[lane];
            a0.x += __half2float(__ushort_as_half(e[0])) * v;
            a0.y += __half2float(__ushort_as_half(e[1])) * v;
            a0.z += __half2float(__ushort_as_half(e[2])) * v;
            a0.w += __half2float(__ushort_as_half(e[3])) * v;
            a1.x += __half2float(__ushort_as_half(e[4])) * v;
            a1.y += __half2float(__ushort_as_half(e[5])) * v;
            a1.z += __half2float(__ushort_as_half(e[6])) * v;
            a1.w += __half2float(__ushort_as_half(e[7])) * v;
        }
    }
    float* orow = out + ((size_t)bin * RPB + g) * Dq + lane * 8;
    __builtin_nontemporal_store(a0, reinterpret_cast<vfloat4*>(orow));
    __builtin_nontemporal_store(a1, reinterpret_cast<vfloat4*>(orow) + 1);
}

// ---------- Pass C: rare-overflow fallback (usually 0 entries, fp32 emb) ----------
__global__ __launch_bounds__(256) void overflow_kernel(
    const int* __restrict__ subnode_ids,
    const int* __restrict__ mb, const int* __restrict__ mn,
    const int* __restrict__ ms, const float* __restrict__ mv,
    const float* __restrict__ emb,
    const int* __restrict__ ovfn, const int* __restrict__ ovf,
    float* __restrict__ out)
{
    int nov = min(*ovfn, OVF_MAX);
    for (int e = blockIdx.x * 256 + threadIdx.x; e < nov; e += gridDim.x * 256) {
        int i = ovf[e];
        int b = mb[i];
        int row = b * Nq + mn[i];
        int tok = subnode_ids[b * Sq + ms[i]];
        float v = mv[i];
        const float* src = emb + (size_t)tok * Dq;
        float* dst = out + (size_t)row * Dq;
        for (int d = 0; d < Dq; d++) unsafeAtomicAdd(dst + d, src[d] * v);
    }
}

extern "C" void kernel_launch(void* const* d_in, const int* in_sizes, int n_in,
                              void* d_out, int out_size, void* d_ws, size_t ws_size,
                              hipStream_t stream) {
    const int*   subnode_ids  = (const int*)d_in[0];
    const int*   mask_batch   = (const int*)d_in[1];
    const int*   mask_node    = (const int*)d_in[2];
    const int*   mask_subnode = (const int*)d_in[3];
    const float* mask_values  = (const float*)d_in[4];
    const float* emb_table    = (const float*)d_in[5];
    float*       out          = (float*)d_out;

    // ws layout: emb16[VOCAB*D halves, 12.86 MB] | binMem[NBIN*BCAP u64, 12.6 MB]
    //          | binCnt[NBIN] | ovfn[1] pad[63] | ovf[OVF_MAX]
    unsigned short* emb16 = (unsigned short*)d_ws;
    u64* binMem = (u64*)(emb16 + (size_t)VOCABq * Dq + 64 /*align pad*/);
    int* binCnt = (int*)(binMem + (size_t)NBIN * BCAP);
    int* ovfn   = binCnt + NBIN;
    int* ovf    = ovfn + 64;

    (void)hipMemsetAsync(binCnt, 0, (NBIN + 64) * sizeof(int), stream);

    const int NQUAD = (VOCABq * Dq) / 4;
    cast_kernel<<<(NQUAD + 255) / 256, 256, 0, stream>>>(emb_table, emb16);
    bin_kernel<<<NNZq / (BTPB * BEPT), BTPB, 0, stream>>>(
        subnode_ids, mask_batch, mask_node, mask_subnode, mask_values,
        binCnt, binMem, ovfn, ovf);
    pool_kernel<<<NBIN, 256, 0, stream>>>(emb16, binCnt, binMem, out);
    overflow_kernel<<<32, 256, 0, stream>>>(
        subnode_ids, mask_batch, mask_node, mask_subnode, mask_values,
        emb_table, ovfn, ovf, out);
}